// Round 4
// baseline (7153.822 us; speedup 1.0000x reference)
//
#include <hip/hip_runtime.h>
#include <hip/hip_bf16.h>

#define D_DIM 1024
#define T_STEPS 1024
#define BATCH 16
#define EPSF 1e-8f
#define MAXR 0.999f

typedef unsigned int u32;
typedef unsigned long long u64;
typedef unsigned short u16;
typedef __attribute__((ext_vector_type(8))) short short8;
typedef __attribute__((ext_vector_type(4))) float floatx4;

__device__ __forceinline__ u16 f2bf(float f) {
  __hip_bfloat16 h = __float2bfloat16(f);
  return *reinterpret_cast<u16*>(&h);
}

// pack h as {bf16 hi | bf16 lo}: hi = bf16(h), lo = bf16(h - hi). Two-plane
// representation recovers h to ~2^-17 relative -- matches f32-h numerics.
__device__ __forceinline__ u32 packhl(float h) {
  const u16 hb = f2bf(h);
  const float fh = __uint_as_float((u32)hb << 16);
  const u16 lb = f2bf(h - fh);
  return ((u32)hb << 16) | lb;
}

// 256-thread block reduction; every thread returns the full sum.
__device__ __forceinline__ float block_reduce_256(float v, float* sred) {
  #pragma unroll
  for (int off = 32; off > 0; off >>= 1) v += __shfl_down(v, off, 64);
  const int w = threadIdx.x >> 6;
  __syncthreads();
  if ((threadIdx.x & 63) == 0) sred[w] = v;
  __syncthreads();
  return sred[0] + sred[1] + sred[2] + sred[3];
}

// out[j] = sum_i W[i][j] * (vin[i] / (||vin|| + eps))
__global__ __launch_bounds__(256) void mv_t(const float* __restrict__ W,
                                            const float* __restrict__ vin,
                                            float* __restrict__ vout) {
  __shared__ float sred[4];
  const int tid = threadIdx.x, j = blockIdx.x;
  const float4 uv = ((const float4*)vin)[tid];
  float ss = uv.x*uv.x + uv.y*uv.y + uv.z*uv.z + uv.w*uv.w;
  ss = block_reduce_256(ss, sred);
  const float s = 1.f / (sqrtf(ss) + EPSF);
  float a = 0.f;
  #pragma unroll
  for (int q = 0; q < 4; ++q) {
    const int i = q*256 + tid;
    a += W[(size_t)i*D_DIM + j] * vin[i];
  }
  a = block_reduce_256(a, sred);
  if (tid == 0) vout[j] = a * s;
}

// out[i] = sum_j W[i][j] * (vin[j] / (||vin|| + eps))
__global__ __launch_bounds__(256) void mv_n(const float* __restrict__ W,
                                            const float* __restrict__ vin,
                                            float* __restrict__ vout) {
  __shared__ float sred[4];
  const int tid = threadIdx.x, i = blockIdx.x;
  const float4 vv = ((const float4*)vin)[tid];
  float ss = vv.x*vv.x + vv.y*vv.y + vv.z*vv.z + vv.w*vv.w;
  ss = block_reduce_256(ss, sred);
  const float s = 1.f / (sqrtf(ss) + EPSF);
  const float4 wv = ((const float4*)(W + (size_t)i*D_DIM))[tid];
  float a = wv.x*vv.x + wv.y*vv.y + wv.z*vv.z + wv.w*vv.w;
  a = block_reduce_256(a, sred);
  if (tid == 0) vout[i] = a * s;
}

// sigma = ||u3_raw||^2 / (||u3_raw|| + eps)   (== |u^T W v| exactly)
__global__ __launch_bounds__(256) void sigma_k(const float* __restrict__ v,
                                               float* __restrict__ sig) {
  __shared__ float sred[4];
  const int tid = threadIdx.x;
  const float4 x4 = ((const float4*)v)[tid];
  float ss = x4.x*x4.x + x4.y*x4.y + x4.z*x4.z + x4.w*x4.w;
  ss = block_reduce_256(ss, sred);
  if (tid == 0) {
    const float n = sqrtf(ss);
    *sig = ss / (n + EPSF);
  }
}

// Weff_bf16[d][k] = bf16( Wh[d][k] * sigmoid(lr[d]) * MAXR / (sigma + eps) )
__global__ __launch_bounds__(256) void make_weff(const float* __restrict__ Wh,
                                                 const float* __restrict__ lr,
                                                 const float* __restrict__ sig,
                                                 u16* __restrict__ Weff) {
  const int idx = blockIdx.x*256 + threadIdx.x;
  const int d = idx >> 8;
  const float sigma = *sig;
  const float r = MAXR / (1.f + expf(-lr[d]));
  const float scale = r / (sigma + EPSF);
  const float4 w = ((const float4*)Wh)[idx];
  ushort4 o;
  o.x = f2bf(w.x*scale); o.y = f2bf(w.y*scale);
  o.z = f2bf(w.z*scale); o.w = f2bf(w.w*scale);
  ((ushort4*)Weff)[idx] = o;
}

// A_pre[m][n] = sum_k X[m][k]*Wx[n][k] + bias[n], bf16 MFMA 16x16x32, 128x128 tiles
__global__ __launch_bounds__(256) void gemm_xwT(const float* __restrict__ X,
                                                const float* __restrict__ Wx,
                                                const float* __restrict__ bias,
                                                float* __restrict__ Apre) {
  __shared__ __align__(16) u16 As[128*32];
  __shared__ __align__(16) u16 Bs[128*32];
  const int tid = threadIdx.x;
  const int bm = blockIdx.x & 127;
  const int bn = blockIdx.x >> 7;
  const int m0 = bm << 7, n0 = bn << 7;
  const int lane = tid & 63, wave = tid >> 6;
  const int wm = (wave & 1) << 6, wn = (wave >> 1) << 6;
  const int fm = lane & 15, kq = lane >> 4;

  floatx4 acc[4][4];
  const floatx4 zero4 = {0.f, 0.f, 0.f, 0.f};
  #pragma unroll
  for (int i = 0; i < 4; ++i)
    #pragma unroll
    for (int j = 0; j < 4; ++j) acc[i][j] = zero4;

  for (int k0 = 0; k0 < 1024; k0 += 32) {
    #pragma unroll
    for (int i = 0; i < 4; ++i) {
      const int c = i*256 + tid;
      const int r = c >> 3, cc = (c & 7) << 2;
      const float4 av = *(const float4*)&X[(size_t)(m0 + r)*1024 + k0 + cc];
      const float4 bv = *(const float4*)&Wx[(size_t)(n0 + r)*1024 + k0 + cc];
      ushort4 ap, bp;
      ap.x = f2bf(av.x); ap.y = f2bf(av.y); ap.z = f2bf(av.z); ap.w = f2bf(av.w);
      bp.x = f2bf(bv.x); bp.y = f2bf(bv.y); bp.z = f2bf(bv.z); bp.w = f2bf(bv.w);
      *(ushort4*)&As[r*32 + cc] = ap;
      *(ushort4*)&Bs[r*32 + cc] = bp;
    }
    __syncthreads();
    short8 afr[4], bfr[4];
    #pragma unroll
    for (int mi = 0; mi < 4; ++mi)
      afr[mi] = *(const short8*)&As[(wm + mi*16 + fm)*32 + kq*8];
    #pragma unroll
    for (int ni = 0; ni < 4; ++ni)
      bfr[ni] = *(const short8*)&Bs[(wn + ni*16 + fm)*32 + kq*8];
    #pragma unroll
    for (int mi = 0; mi < 4; ++mi)
      #pragma unroll
      for (int ni = 0; ni < 4; ++ni)
        acc[mi][ni] = __builtin_amdgcn_mfma_f32_16x16x32_bf16(afr[mi], bfr[ni], acc[mi][ni], 0, 0, 0);
    __syncthreads();
  }
  const int cn = lane & 15, rb = (lane >> 4) << 2;
  #pragma unroll
  for (int mi = 0; mi < 4; ++mi) {
    #pragma unroll
    for (int ni = 0; ni < 4; ++ni) {
      const int n = n0 + wn + ni*16 + cn;
      const float bv = bias[n];
      #pragma unroll
      for (int r = 0; r < 4; ++r) {
        const int m = m0 + wm + mi*16 + rb + r;
        Apre[(size_t)m*1024 + n] = acc[mi][ni][r] + bv;
      }
    }
  }
}

// Persistent scan v6: 8 WGs x 256 threads. WG owns 128 dims x ALL 16 batches --
// the recurrence is H[16][1024] @ W^T, so batch == MFMA M=16. Per step:
//   - pull h[t] DIRECTLY in MFMA A-fragment layout from comm (u32 {bf16 hi|lo}
//     per value; agent-scope u64 loads; each wave pulls a disjoint K-quarter
//     = 16 KB -> 64 KB/WG, no redundancy, no LDS staging of H).
//   - 2 MFMA passes (hi, lo) against W frags held in VGPRs (256 regs/lane)
//     recover f32-precision h; W never touches LDS.
//   - 4-way K-partial reduction via 32 KB LDS (conflict-free b128).
//   - detection: 7 foreign flags, polled by 4 waves (32 pollers chip-wide;
//     v5 lesson: poller count x footprint, not RT count, ruled the fabric).
// Ping-pong comm[t&1]; flag[wg]=t+1 after the drain barrier certifies h[t+1].
__global__ __launch_bounds__(256, 1) void scan_rnn(const float* __restrict__ Z,
                                                   const float* __restrict__ H0,
                                                   const u16* __restrict__ Weff,
                                                   float* __restrict__ outs,
                                                   float* __restrict__ hall,
                                                   u32* __restrict__ comm,
                                                   u32* __restrict__ flg) {
  __shared__ __align__(16) float red[4][8][64][4];   // 32 KB partial C-frags
  const int tid = threadIdx.x;
  const int wg = blockIdx.x;          // 0..7, owns dims [wg*128, wg*128+128)
  const int lane = tid & 63, wv = tid >> 6;   // wv = K-group 0..3
  const int frow = lane & 15;         // fragment row (batch for A, dim for B)
  const int kq = lane >> 4;           // k-subchunk 0..3 (8 bf16 each)

  // W fragments in registers: wave wv covers chunks wv*8 .. wv*8+7 (k-quarter),
  // all 8 n-tiles. 64 frags x 16B = 256 VGPRs.
  short8 Wf[8][8];
  #pragma unroll
  for (int c2 = 0; c2 < 8; ++c2) {
    const int chunk = wv*8 + c2;
    #pragma unroll
    for (int nt = 0; nt < 8; ++nt)
      Wf[c2][nt] = *(const short8*)&Weff[(size_t)(wg*128 + nt*16 + frow)*1024 + chunk*32 + kq*8];
  }

  // hall[0] = H0 for this WG's dim range (host output only)
  #pragma unroll
  for (int i = 0; i < 8; ++i) {
    const int idx = i*256 + tid;      // 0..2047
    const int b = idx >> 7, dd = idx & 127;
    hall[(size_t)b*D_DIM + wg*128 + dd] = H0[(size_t)b*D_DIM + wg*128 + dd];
  }

  const int m_base = kq << 2;               // C-frag rows (batch) m_base..+3
  const int dcol = wg*128 + frow;           // C-frag col base (dim), + nt*16
  int pat = 1 << 22;                        // poll budget: deadlock -> clean exit

  for (int t = 0; t < T_STEPS; ++t) {
    // Prefetch epilogue operands (this wave finalizes n-tiles 2wv, 2wv+1)
    float ap[2][4], zp[2][4];
    #pragma unroll
    for (int p = 0; p < 2; ++p)
      #pragma unroll
      for (int r = 0; r < 4; ++r) {
        const size_t adr = (size_t)t*16384 + (size_t)(m_base + r)*1024 + dcol + (wv*2 + p)*16;
        ap[p][r] = outs[adr];
        zp[p][r] = Z[adr];
      }

    // Acquire h[t] in fragment layout: q[c2*4+i] = u64 covering k0+2i, k0+2i+1
    u64 q[32];
    if (t == 0) {
      #pragma unroll
      for (int c2 = 0; c2 < 8; ++c2) {
        const int k0 = (wv*8 + c2)*32 + kq*8;
        #pragma unroll
        for (int i = 0; i < 4; ++i) {
          const float2 h2 = *(const float2*)&H0[(size_t)frow*1024 + k0 + i*2];
          q[c2*4+i] = ((u64)packhl(h2.y) << 32) | packhl(h2.x);
        }
      }
    } else {
      // Poll the 7 foreign flags (own data certified by our own drain barrier)
      const u32 tgt = (u32)t;
      const int fi = lane & 7;
      for (;;) {
        u32 v = tgt;
        if (fi != wg)
          v = __hip_atomic_load(&flg[fi << 5], __ATOMIC_RELAXED, __HIP_MEMORY_SCOPE_AGENT);
        if (__all((int)(v >= tgt))) break;
        if (--pat <= 0) break;
      }
      const u64* cbase = (const u64*)(comm + (size_t)(t & 1)*16384);
      #pragma unroll
      for (int c2 = 0; c2 < 8; ++c2) {
        const int k0 = (wv*8 + c2)*32 + kq*8;
        const int e = (frow*1024 + k0) >> 1;
        #pragma unroll
        for (int i = 0; i < 4; ++i)
          q[c2*4+i] = __hip_atomic_load(cbase + e + i, __ATOMIC_RELAXED, __HIP_MEMORY_SCOPE_AGENT);
      }
    }

    // MFMA: unpack {hi|lo} planes per chunk, 2 passes vs shared W frags
    floatx4 acc[8];
    const floatx4 zero4 = {0.f, 0.f, 0.f, 0.f};
    #pragma unroll
    for (int nt = 0; nt < 8; ++nt) acc[nt] = zero4;
    #pragma unroll
    for (int c2 = 0; c2 < 8; ++c2) {
      int4 hw, lw;
      #pragma unroll
      for (int i = 0; i < 4; ++i) {
        const u32 plo = (u32)q[c2*4+i];
        const u32 phi = (u32)(q[c2*4+i] >> 32);
        hw[i] = (int)__builtin_amdgcn_perm(phi, plo, 0x07060302u);  // hi bf16 pair
        lw[i] = (int)__builtin_amdgcn_perm(phi, plo, 0x05040100u);  // lo bf16 pair
      }
      const short8 ah = *reinterpret_cast<short8*>(&hw);
      const short8 al = *reinterpret_cast<short8*>(&lw);
      #pragma unroll
      for (int nt = 0; nt < 8; ++nt) {
        acc[nt] = __builtin_amdgcn_mfma_f32_16x16x32_bf16(ah, Wf[c2][nt], acc[nt], 0, 0, 0);
        acc[nt] = __builtin_amdgcn_mfma_f32_16x16x32_bf16(al, Wf[c2][nt], acc[nt], 0, 0, 0);
      }
    }

    // 4-way K-partial reduction through LDS; wave wv finalizes nt = 2wv, 2wv+1
    #pragma unroll
    for (int nt = 0; nt < 8; ++nt)
      *(floatx4*)&red[wv][nt][lane][0] = acc[nt];
    __syncthreads();
    floatx4 fin0 = zero4, fin1 = zero4;
    #pragma unroll
    for (int w = 0; w < 4; ++w) {
      fin0 += *(const floatx4*)&red[w][wv*2    ][lane][0];
      fin1 += *(const floatx4*)&red[w][wv*2 + 1][lane][0];
    }

    // Epilogue: tanh, silu gate, outs/hall stores, publish packed h[t+1]
    #pragma unroll
    for (int p = 0; p < 2; ++p) {
      const floatx4 f = p ? fin1 : fin0;
      #pragma unroll
      for (int r = 0; r < 4; ++r) {
        const size_t adr = (size_t)t*16384 + (size_t)(m_base + r)*1024 + dcol + (wv*2 + p)*16;
        const float hn = tanhf(f[r] + ap[p][r]);
        const float zz = zp[p][r];
        outs[adr] = hn * (zz / (1.f + expf(-zz)));
        hall[adr + 16384] = hn;
        __hip_atomic_store(&comm[(size_t)((t + 1) & 1)*16384 + (size_t)(m_base + r)*1024 + dcol + (wv*2 + p)*16],
                           packhl(hn), __ATOMIC_RELAXED, __HIP_MEMORY_SCOPE_AGENT);
      }
    }
    __syncthreads();   // drains every wave's comm stores (vmcnt 0 at barrier)
    if (tid == 0)
      __hip_atomic_store(&flg[wg << 5], (u32)(t + 1),
                         __ATOMIC_RELAXED, __HIP_MEMORY_SCOPE_AGENT);
  }
}

extern "C" void kernel_launch(void* const* d_in, const int* in_sizes, int n_in,
                              void* d_out, int out_size, void* d_ws, size_t ws_size,
                              hipStream_t stream) {
  const float* x  = (const float*)d_in[0];
  const float* z  = (const float*)d_in[1];
  const float* h0 = (const float*)d_in[2];
  const float* Wx = (const float*)d_in[3];
  const float* Wh = (const float*)d_in[4];
  const float* lr = (const float*)d_in[5];
  const float* bb = (const float*)d_in[6];
  const float* u0 = (const float*)d_in[7];

  float* outp = (float*)d_out;
  float* outs = outp;                                    // [1024][16][1024]
  float* hall = outp + (size_t)T_STEPS*BATCH*D_DIM;      // [1025][16][1024]

  char* ws = (char*)d_ws;
  u16* Weff = (u16*)ws;                         // 2 MiB bf16
  float* tA  = (float*)(ws + 2097152);
  float* tB  = (float*)(ws + 2101248);
  float* sg  = (float*)(ws + 2105344);
  u32* comm  = (u32*)(ws + 2105600);            // ping-pong 2 x [16][1024] u32 = 128 KiB
  u32* flg   = (u32*)(ws + 2105600 + 131072);   // 8 flags, 128B apart = 1 KiB

  hipMemsetAsync(flg, 0, 8*128, stream);

  // 3-step power iteration (normalization folded into each matvec)
  mv_t<<<1024, 256, 0, stream>>>(Wh, u0, tA);   // v1_raw
  mv_n<<<1024, 256, 0, stream>>>(Wh, tA, tB);   // u1_raw
  mv_t<<<1024, 256, 0, stream>>>(Wh, tB, tA);   // v2_raw
  mv_n<<<1024, 256, 0, stream>>>(Wh, tA, tB);   // u2_raw
  mv_t<<<1024, 256, 0, stream>>>(Wh, tB, tA);   // v3_raw
  mv_n<<<1024, 256, 0, stream>>>(Wh, tA, tB);   // u3_raw = W v3
  sigma_k<<<1, 256, 0, stream>>>(tB, sg);
  make_weff<<<1024, 256, 0, stream>>>(Wh, lr, sg, Weff);

  // A_pre = x @ Wx^T + b, written into the outs region (overwritten in-place by scan)
  gemm_xwT<<<1024, 256, 0, stream>>>(x, Wx, bb, outs);

  // Persistent sequential scan: 8 WGs, batch-as-M MFMA, W in registers
  scan_rnn<<<8, 256, 0, stream>>>(z, h0, Weff, outs, hall, comm, flg);
}

// Round 5
// 3517.007 us; speedup vs baseline: 2.0341x; 2.0341x over previous
//
#include <hip/hip_runtime.h>
#include <hip/hip_bf16.h>

#define D_DIM 1024
#define T_STEPS 1024
#define BATCH 16
#define EPSF 1e-8f
#define MAXR 0.999f

typedef unsigned int u32;
typedef unsigned long long u64;
typedef unsigned short u16;
typedef __attribute__((ext_vector_type(8))) short short8;
typedef __attribute__((ext_vector_type(4))) float floatx4;

__device__ __forceinline__ float bf_lo(u32 u) { return __uint_as_float(u << 16); }
__device__ __forceinline__ float bf_hi(u32 u) { return __uint_as_float(u & 0xffff0000u); }

__device__ __forceinline__ u16 f2bf(float f) {
  __hip_bfloat16 h = __float2bfloat16(f);
  return *reinterpret_cast<u16*>(&h);
}

// 256-thread block reduction; every thread returns the full sum.
__device__ __forceinline__ float block_reduce_256(float v, float* sred) {
  #pragma unroll
  for (int off = 32; off > 0; off >>= 1) v += __shfl_down(v, off, 64);
  const int w = threadIdx.x >> 6;
  __syncthreads();
  if ((threadIdx.x & 63) == 0) sred[w] = v;
  __syncthreads();
  return sred[0] + sred[1] + sred[2] + sred[3];
}

// out[j] = sum_i W[i][j] * (vin[i] / (||vin|| + eps))
__global__ __launch_bounds__(256) void mv_t(const float* __restrict__ W,
                                            const float* __restrict__ vin,
                                            float* __restrict__ vout) {
  __shared__ float sred[4];
  const int tid = threadIdx.x, j = blockIdx.x;
  const float4 uv = ((const float4*)vin)[tid];
  float ss = uv.x*uv.x + uv.y*uv.y + uv.z*uv.z + uv.w*uv.w;
  ss = block_reduce_256(ss, sred);
  const float s = 1.f / (sqrtf(ss) + EPSF);
  float a = 0.f;
  #pragma unroll
  for (int q = 0; q < 4; ++q) {
    const int i = q*256 + tid;
    a += W[(size_t)i*D_DIM + j] * vin[i];
  }
  a = block_reduce_256(a, sred);
  if (tid == 0) vout[j] = a * s;
}

// out[i] = sum_j W[i][j] * (vin[j] / (||vin|| + eps))
__global__ __launch_bounds__(256) void mv_n(const float* __restrict__ W,
                                            const float* __restrict__ vin,
                                            float* __restrict__ vout) {
  __shared__ float sred[4];
  const int tid = threadIdx.x, i = blockIdx.x;
  const float4 vv = ((const float4*)vin)[tid];
  float ss = vv.x*vv.x + vv.y*vv.y + vv.z*vv.z + vv.w*vv.w;
  ss = block_reduce_256(ss, sred);
  const float s = 1.f / (sqrtf(ss) + EPSF);
  const float4 wv = ((const float4*)(W + (size_t)i*D_DIM))[tid];
  float a = wv.x*vv.x + wv.y*vv.y + wv.z*vv.z + wv.w*vv.w;
  a = block_reduce_256(a, sred);
  if (tid == 0) vout[i] = a * s;
}

// sigma = ||u3_raw||^2 / (||u3_raw|| + eps)   (== |u^T W v| exactly)
__global__ __launch_bounds__(256) void sigma_k(const float* __restrict__ v,
                                               float* __restrict__ sig) {
  __shared__ float sred[4];
  const int tid = threadIdx.x;
  const float4 x4 = ((const float4*)v)[tid];
  float ss = x4.x*x4.x + x4.y*x4.y + x4.z*x4.z + x4.w*x4.w;
  ss = block_reduce_256(ss, sred);
  if (tid == 0) {
    const float n = sqrtf(ss);
    *sig = ss / (n + EPSF);
  }
}

// Weff_bf16[d][k] = bf16( Wh[d][k] * sigmoid(lr[d]) * MAXR / (sigma + eps) )
__global__ __launch_bounds__(256) void make_weff(const float* __restrict__ Wh,
                                                 const float* __restrict__ lr,
                                                 const float* __restrict__ sig,
                                                 u16* __restrict__ Weff) {
  const int idx = blockIdx.x*256 + threadIdx.x;
  const int d = idx >> 8;
  const float sigma = *sig;
  const float r = MAXR / (1.f + expf(-lr[d]));
  const float scale = r / (sigma + EPSF);
  const float4 w = ((const float4*)Wh)[idx];
  ushort4 o;
  o.x = f2bf(w.x*scale); o.y = f2bf(w.y*scale);
  o.z = f2bf(w.z*scale); o.w = f2bf(w.w*scale);
  ((ushort4*)Weff)[idx] = o;
}

// A_pre[m][n] = sum_k X[m][k]*Wx[n][k] + bias[n], bf16 MFMA 16x16x32, 128x128 tiles
__global__ __launch_bounds__(256) void gemm_xwT(const float* __restrict__ X,
                                                const float* __restrict__ Wx,
                                                const float* __restrict__ bias,
                                                float* __restrict__ Apre) {
  __shared__ __align__(16) u16 As[128*32];
  __shared__ __align__(16) u16 Bs[128*32];
  const int tid = threadIdx.x;
  const int bm = blockIdx.x & 127;
  const int bn = blockIdx.x >> 7;
  const int m0 = bm << 7, n0 = bn << 7;
  const int lane = tid & 63, wave = tid >> 6;
  const int wm = (wave & 1) << 6, wn = (wave >> 1) << 6;
  const int fm = lane & 15, kq = lane >> 4;

  floatx4 acc[4][4];
  const floatx4 zero4 = {0.f, 0.f, 0.f, 0.f};
  #pragma unroll
  for (int i = 0; i < 4; ++i)
    #pragma unroll
    for (int j = 0; j < 4; ++j) acc[i][j] = zero4;

  for (int k0 = 0; k0 < 1024; k0 += 32) {
    #pragma unroll
    for (int i = 0; i < 4; ++i) {
      const int c = i*256 + tid;
      const int r = c >> 3, cc = (c & 7) << 2;
      const float4 av = *(const float4*)&X[(size_t)(m0 + r)*1024 + k0 + cc];
      const float4 bv = *(const float4*)&Wx[(size_t)(n0 + r)*1024 + k0 + cc];
      ushort4 ap, bp;
      ap.x = f2bf(av.x); ap.y = f2bf(av.y); ap.z = f2bf(av.z); ap.w = f2bf(av.w);
      bp.x = f2bf(bv.x); bp.y = f2bf(bv.y); bp.z = f2bf(bv.z); bp.w = f2bf(bv.w);
      *(ushort4*)&As[r*32 + cc] = ap;
      *(ushort4*)&Bs[r*32 + cc] = bp;
    }
    __syncthreads();
    short8 afr[4], bfr[4];
    #pragma unroll
    for (int mi = 0; mi < 4; ++mi)
      afr[mi] = *(const short8*)&As[(wm + mi*16 + fm)*32 + kq*8];
    #pragma unroll
    for (int ni = 0; ni < 4; ++ni)
      bfr[ni] = *(const short8*)&Bs[(wn + ni*16 + fm)*32 + kq*8];
    #pragma unroll
    for (int mi = 0; mi < 4; ++mi)
      #pragma unroll
      for (int ni = 0; ni < 4; ++ni)
        acc[mi][ni] = __builtin_amdgcn_mfma_f32_16x16x32_bf16(afr[mi], bfr[ni], acc[mi][ni], 0, 0, 0);
    __syncthreads();
  }
  const int cn = lane & 15, rb = (lane >> 4) << 2;
  #pragma unroll
  for (int mi = 0; mi < 4; ++mi) {
    #pragma unroll
    for (int ni = 0; ni < 4; ++ni) {
      const int n = n0 + wn + ni*16 + cn;
      const float bv = bias[n];
      #pragma unroll
      for (int r = 0; r < 4; ++r) {
        const int m = m0 + wm + mi*16 + rb + r;
        Apre[(size_t)m*1024 + n] = acc[mi][ni][r] + bv;
      }
    }
  }
}

// Persistent scan v7: v4's topology (256 wgs = 16 batch x 16 slices, 1024 thr)
// with the three measured taxes removed:
//  1. W slice in f32 REGISTERS (64 VGPR): dot = 64 pure v_fma, no bf16 unpacks
//     (v4's largest VALUBusy term).
//  2. Producer lanes publish {f32 h | u32 tag} u64 packets DIRECTLY at tanh
//     retire (no wave-15 funnel; barrier's implicit vmcnt(0) is the drain).
//     Consumers SPECULATIVELY load packets at loop top (in flight during the
//     flag poll; drained free by the barrier), validate tags after the flag
//     barrier; hit -> no data-RT on critical path; miss -> ONE guaranteed
//     reload (flags certify visibility). No retry loops anywhere (v3/v5
//     lesson); only 16 lanes/WG poll 15 padded flag words, sleep-free.
//  3. tanh/silu via v_exp_f32 + v_rcp_f32 (3 instrs, on the publish path).
// Ping-pong comm[t&1]; tag in slot t&1 for h[t] is t+1 (monotone, >= check).
__global__ __launch_bounds__(1024, 4) void scan_rnn(const float* __restrict__ Z,
                                                    const float* __restrict__ H0,
                                                    const u16* __restrict__ Weff,
                                                    float* __restrict__ outs,
                                                    float* __restrict__ hall,
                                                    u64* __restrict__ comm,
                                                    u32* __restrict__ flg) {
  __shared__ __align__(16) float Hl[1024];   // h[t], float4 units XOR-swizzled
  __shared__ float hOwn[64];                 // own fresh slice (no self round trip)
  const int tid = threadIdx.x;
  const int b = blockIdx.x & 15;      // batch row
  const int s = blockIdx.x >> 4;      // dim-slice 0..15
  const int d0 = s << 6;
  const int lane = tid & 63, wv = tid >> 6;
  const int kc = lane & 15;           // k-chunk of 64 floats
  const int kcl = kc & 7;
  const int dl = (wv << 2) + (lane >> 4);   // 0..63 dim within slice
  const int row = d0 + dl;

  // W row chunk in f32 registers: 64 floats (bf16 -> f32 widening is exact)
  float wf[64];
  {
    const uint4* Wg = (const uint4*)Weff;   // 128 uint4 per row
    #pragma unroll
    for (int j = 0; j < 8; ++j) {
      const uint4 wp = Wg[(size_t)row*128 + (kc << 3) + j];
      wf[j*8+0] = bf_lo(wp.x); wf[j*8+1] = bf_hi(wp.x);
      wf[j*8+2] = bf_lo(wp.y); wf[j*8+3] = bf_hi(wp.y);
      wf[j*8+4] = bf_lo(wp.z); wf[j*8+5] = bf_hi(wp.z);
      wf[j*8+6] = bf_lo(wp.w); wf[j*8+7] = bf_hi(wp.w);
    }
  }

  // hall[0] slice (host output only)
  if (tid < 64)
    hall[(size_t)b*D_DIM + d0 + tid] = H0[b*D_DIM + d0 + tid];

  const float4* H4 = (const float4*)Hl;
  const bool stager = (tid < 256);                 // float4 unit = tid, dims 4tid..4tid+3
  const bool ownstage = stager && ((tid >> 4) == s);
  u64* const commDim = comm + (size_t)b*D_DIM + (tid << 2);   // + slot*BATCH*D_DIM
  int pat = 1 << 21;                  // poll budget: deadlock -> clean finish, no hang

  for (int t = 0; t < T_STEPS; ++t) {
    const size_t base = (size_t)t*(BATCH*D_DIM) + (size_t)b*D_DIM + row;
    // Prefetch epilogue operands (addresses independent of h)
    float a_pre = 0.f, zv = 0.f;
    if (kc == 0) { a_pre = outs[base]; zv = Z[base]; }

    // Phase A: speculative packet loads (foreign), LDS writes (own/t0),
    // flag poll (wave 15 lanes 0..15). All overlap; barrier drains the loads.
    u64 p0 = 0, p1 = 0, p2 = 0, p3 = 0;
    bool foreign = false;
    if (stager) {
      float4 hv;
      if (t == 0) {
        hv = ((const float4*)(H0 + (size_t)b*D_DIM))[tid];
        ((float4*)Hl)[tid ^ ((tid >> 4) & 7)] = hv;
      } else if (ownstage) {
        const float* ho = &hOwn[(tid & 15) << 2];
        hv.x = ho[0]; hv.y = ho[1]; hv.z = ho[2]; hv.w = ho[3];
        ((float4*)Hl)[tid ^ ((tid >> 4) & 7)] = hv;
      } else {
        foreign = true;
        u64* hp = commDim + (size_t)(t & 1)*(BATCH*D_DIM);
        p0 = __hip_atomic_load(hp + 0, __ATOMIC_RELAXED, __HIP_MEMORY_SCOPE_AGENT);
        p1 = __hip_atomic_load(hp + 1, __ATOMIC_RELAXED, __HIP_MEMORY_SCOPE_AGENT);
        p2 = __hip_atomic_load(hp + 2, __ATOMIC_RELAXED, __HIP_MEMORY_SCOPE_AGENT);
        p3 = __hip_atomic_load(hp + 3, __ATOMIC_RELAXED, __HIP_MEMORY_SCOPE_AGENT);
      }
    }
    if (t > 0 && wv == 15 && (lane & 48) == 0) {   // lanes 0..15 of wave 15
      const int fi = lane & 15;
      if (fi != s) {
        const u32 tgt = (u32)(t + 1);
        while (pat > 0) {
          const u32 v = __hip_atomic_load(&flg[((b << 4) + fi) << 5],
                                          __ATOMIC_RELAXED, __HIP_MEMORY_SCOPE_AGENT);
          if (v >= tgt) break;
          --pat;
        }
      }
    }
    __syncthreads();   // flags confirmed; spec loads drained into registers

    // Phase B: validate tags; stale -> one reload (now guaranteed fresh)
    if (foreign) {
      const u32 tgt = (u32)(t + 1);
      if (((u32)p0 < tgt) | ((u32)p1 < tgt) | ((u32)p2 < tgt) | ((u32)p3 < tgt)) {
        u64* hp = commDim + (size_t)(t & 1)*(BATCH*D_DIM);
        p0 = __hip_atomic_load(hp + 0, __ATOMIC_RELAXED, __HIP_MEMORY_SCOPE_AGENT);
        p1 = __hip_atomic_load(hp + 1, __ATOMIC_RELAXED, __HIP_MEMORY_SCOPE_AGENT);
        p2 = __hip_atomic_load(hp + 2, __ATOMIC_RELAXED, __HIP_MEMORY_SCOPE_AGENT);
        p3 = __hip_atomic_load(hp + 3, __ATOMIC_RELAXED, __HIP_MEMORY_SCOPE_AGENT);
      }
      float4 hv;
      hv.x = __uint_as_float((u32)(p0 >> 32));
      hv.y = __uint_as_float((u32)(p1 >> 32));
      hv.z = __uint_as_float((u32)(p2 >> 32));
      hv.w = __uint_as_float((u32)(p3 >> 32));
      ((float4*)Hl)[tid ^ ((tid >> 4) & 7)] = hv;
    }
    __syncthreads();

    // Phase C: dot for dim row, k-chunk kc (64 elems), W from f32 registers
    float acc = 0.f;
    #pragma unroll
    for (int j = 0; j < 8; ++j) {
      const float4 ha = H4[(kc << 4) + (((j << 1)    ) ^ kcl)];
      const float4 hb = H4[(kc << 4) + (((j << 1) + 1) ^ kcl)];
      acc += wf[j*8+0]*ha.x + wf[j*8+1]*ha.y + wf[j*8+2]*ha.z + wf[j*8+3]*ha.w;
      acc += wf[j*8+4]*hb.x + wf[j*8+5]*hb.y + wf[j*8+6]*hb.z + wf[j*8+7]*hb.w;
    }
    // reduce across the 16 kc lanes (lane bits 0..3)
    acc += __shfl_xor(acc, 1, 64);
    acc += __shfl_xor(acc, 2, 64);
    acc += __shfl_xor(acc, 4, 64);
    acc += __shfl_xor(acc, 8, 64);

    if (kc == 0) {
      // fast tanh: 1 - 2/(e^{2v}+1) via v_exp_f32 (2^x) + v_rcp_f32
      const float v = acc + a_pre;
      const float e = __builtin_amdgcn_exp2f(v * 2.8853900817779268f);
      const float hn = 1.f - 2.f*__builtin_amdgcn_rcpf(e + 1.f);
      // publish FIRST: self-validating packet, tag = t+2 for slot (t+1)&1
      const u64 pkt = ((u64)__float_as_uint(hn) << 32) | (u32)(t + 2);
      __hip_atomic_store(&comm[(size_t)((t + 1) & 1)*(BATCH*D_DIM) + (size_t)b*D_DIM + row],
                         pkt, __ATOMIC_RELAXED, __HIP_MEMORY_SCOPE_AGENT);
      hOwn[dl] = hn;
      // silu gate: zz * 1/(1+e^{-zz})
      const float eg = __builtin_amdgcn_exp2f(zv * -1.4426950408889634f);
      outs[base] = hn * (zv * __builtin_amdgcn_rcpf(1.f + eg));
      hall[base + BATCH*D_DIM] = hn;
    }
    __syncthreads();   // drains every wave's comm stores; hOwn/Hl lifecycle
    if (tid == 0)
      __hip_atomic_store(&flg[((b << 4) + s) << 5], (u32)(t + 2),
                         __ATOMIC_RELAXED, __HIP_MEMORY_SCOPE_AGENT);
  }
}

extern "C" void kernel_launch(void* const* d_in, const int* in_sizes, int n_in,
                              void* d_out, int out_size, void* d_ws, size_t ws_size,
                              hipStream_t stream) {
  const float* x  = (const float*)d_in[0];
  const float* z  = (const float*)d_in[1];
  const float* h0 = (const float*)d_in[2];
  const float* Wx = (const float*)d_in[3];
  const float* Wh = (const float*)d_in[4];
  const float* lr = (const float*)d_in[5];
  const float* bb = (const float*)d_in[6];
  const float* u0 = (const float*)d_in[7];

  float* outp = (float*)d_out;
  float* outs = outp;                                    // [1024][16][1024]
  float* hall = outp + (size_t)T_STEPS*BATCH*D_DIM;      // [1025][16][1024]

  char* ws = (char*)d_ws;
  u16* Weff = (u16*)ws;                         // 2 MiB bf16
  float* tA  = (float*)(ws + 2097152);
  float* tB  = (float*)(ws + 2101248);
  float* sg  = (float*)(ws + 2105344);
  u64* comm  = (u64*)(ws + 2105600);            // ping-pong 2 x [16][1024] u64 = 256 KiB
  u32* flg   = (u32*)(ws + 2105600 + 262144);   // 256 flags, 128B apart = 32 KiB

  hipMemsetAsync(comm, 0, 262144 + 32768, stream);  // comm tags + flags must start 0

  // 3-step power iteration (normalization folded into each matvec)
  mv_t<<<1024, 256, 0, stream>>>(Wh, u0, tA);   // v1_raw
  mv_n<<<1024, 256, 0, stream>>>(Wh, tA, tB);   // u1_raw
  mv_t<<<1024, 256, 0, stream>>>(Wh, tB, tA);   // v2_raw
  mv_n<<<1024, 256, 0, stream>>>(Wh, tA, tB);   // u2_raw
  mv_t<<<1024, 256, 0, stream>>>(Wh, tB, tA);   // v3_raw
  mv_n<<<1024, 256, 0, stream>>>(Wh, tA, tB);   // u3_raw = W v3
  sigma_k<<<1, 256, 0, stream>>>(tB, sg);
  make_weff<<<1024, 256, 0, stream>>>(Wh, lr, sg, Weff);

  // A_pre = x @ Wx^T + b, written into the outs region (overwritten in-place by scan)
  gemm_xwT<<<1024, 256, 0, stream>>>(x, Wx, bb, outs);

  // Persistent sequential scan: spec-load + flag-certify, one data-RT dodged
  scan_rnn<<<256, 1024, 0, stream>>>(z, h0, Weff, outs, hall, comm, flg);
}

// Round 6
// 2830.376 us; speedup vs baseline: 2.5275x; 1.2426x over previous
//
#include <hip/hip_runtime.h>
#include <hip/hip_bf16.h>

#define D_DIM 1024
#define T_STEPS 1024
#define BATCH 16
#define EPSF 1e-8f
#define MAXR 0.999f

typedef unsigned int u32;
typedef unsigned long long u64;
typedef unsigned short u16;
typedef __attribute__((ext_vector_type(8))) short short8;
typedef __attribute__((ext_vector_type(4))) float floatx4;

__device__ __forceinline__ float bf_lo(u32 u) { return __uint_as_float(u << 16); }
__device__ __forceinline__ float bf_hi(u32 u) { return __uint_as_float(u & 0xffff0000u); }

__device__ __forceinline__ u16 f2bf(float f) {
  __hip_bfloat16 h = __float2bfloat16(f);
  return *reinterpret_cast<u16*>(&h);
}

// 256-thread block reduction; every thread returns the full sum.
__device__ __forceinline__ float block_reduce_256(float v, float* sred) {
  #pragma unroll
  for (int off = 32; off > 0; off >>= 1) v += __shfl_down(v, off, 64);
  const int w = threadIdx.x >> 6;
  __syncthreads();
  if ((threadIdx.x & 63) == 0) sred[w] = v;
  __syncthreads();
  return sred[0] + sred[1] + sred[2] + sred[3];
}

// out[j] = sum_i W[i][j] * (vin[i] / (||vin|| + eps))
__global__ __launch_bounds__(256) void mv_t(const float* __restrict__ W,
                                            const float* __restrict__ vin,
                                            float* __restrict__ vout) {
  __shared__ float sred[4];
  const int tid = threadIdx.x, j = blockIdx.x;
  const float4 uv = ((const float4*)vin)[tid];
  float ss = uv.x*uv.x + uv.y*uv.y + uv.z*uv.z + uv.w*uv.w;
  ss = block_reduce_256(ss, sred);
  const float s = 1.f / (sqrtf(ss) + EPSF);
  float a = 0.f;
  #pragma unroll
  for (int q = 0; q < 4; ++q) {
    const int i = q*256 + tid;
    a += W[(size_t)i*D_DIM + j] * vin[i];
  }
  a = block_reduce_256(a, sred);
  if (tid == 0) vout[j] = a * s;
}

// out[i] = sum_j W[i][j] * (vin[j] / (||vin|| + eps))
__global__ __launch_bounds__(256) void mv_n(const float* __restrict__ W,
                                            const float* __restrict__ vin,
                                            float* __restrict__ vout) {
  __shared__ float sred[4];
  const int tid = threadIdx.x, i = blockIdx.x;
  const float4 vv = ((const float4*)vin)[tid];
  float ss = vv.x*vv.x + vv.y*vv.y + vv.z*vv.z + vv.w*vv.w;
  ss = block_reduce_256(ss, sred);
  const float s = 1.f / (sqrtf(ss) + EPSF);
  const float4 wv = ((const float4*)(W + (size_t)i*D_DIM))[tid];
  float a = wv.x*vv.x + wv.y*vv.y + wv.z*vv.z + wv.w*vv.w;
  a = block_reduce_256(a, sred);
  if (tid == 0) vout[i] = a * s;
}

// sigma = ||u3_raw||^2 / (||u3_raw|| + eps)   (== |u^T W v| exactly)
__global__ __launch_bounds__(256) void sigma_k(const float* __restrict__ v,
                                               float* __restrict__ sig) {
  __shared__ float sred[4];
  const int tid = threadIdx.x;
  const float4 x4 = ((const float4*)v)[tid];
  float ss = x4.x*x4.x + x4.y*x4.y + x4.z*x4.z + x4.w*x4.w;
  ss = block_reduce_256(ss, sred);
  if (tid == 0) {
    const float n = sqrtf(ss);
    *sig = ss / (n + EPSF);
  }
}

// Weff_bf16[d][k] = bf16( Wh[d][k] * sigmoid(lr[d]) * MAXR / (sigma + eps) )
__global__ __launch_bounds__(256) void make_weff(const float* __restrict__ Wh,
                                                 const float* __restrict__ lr,
                                                 const float* __restrict__ sig,
                                                 u16* __restrict__ Weff) {
  const int idx = blockIdx.x*256 + threadIdx.x;
  const int d = idx >> 8;
  const float sigma = *sig;
  const float r = MAXR / (1.f + expf(-lr[d]));
  const float scale = r / (sigma + EPSF);
  const float4 w = ((const float4*)Wh)[idx];
  ushort4 o;
  o.x = f2bf(w.x*scale); o.y = f2bf(w.y*scale);
  o.z = f2bf(w.z*scale); o.w = f2bf(w.w*scale);
  ((ushort4*)Weff)[idx] = o;
}

// A_pre[m][n] = sum_k X[m][k]*Wx[n][k] + bias[n], bf16 MFMA 16x16x32, 128x128 tiles
__global__ __launch_bounds__(256) void gemm_xwT(const float* __restrict__ X,
                                                const float* __restrict__ Wx,
                                                const float* __restrict__ bias,
                                                float* __restrict__ Apre) {
  __shared__ __align__(16) u16 As[128*32];
  __shared__ __align__(16) u16 Bs[128*32];
  const int tid = threadIdx.x;
  const int bm = blockIdx.x & 127;
  const int bn = blockIdx.x >> 7;
  const int m0 = bm << 7, n0 = bn << 7;
  const int lane = tid & 63, wave = tid >> 6;
  const int wm = (wave & 1) << 6, wn = (wave >> 1) << 6;
  const int fm = lane & 15, kq = lane >> 4;

  floatx4 acc[4][4];
  const floatx4 zero4 = {0.f, 0.f, 0.f, 0.f};
  #pragma unroll
  for (int i = 0; i < 4; ++i)
    #pragma unroll
    for (int j = 0; j < 4; ++j) acc[i][j] = zero4;

  for (int k0 = 0; k0 < 1024; k0 += 32) {
    #pragma unroll
    for (int i = 0; i < 4; ++i) {
      const int c = i*256 + tid;
      const int r = c >> 3, cc = (c & 7) << 2;
      const float4 av = *(const float4*)&X[(size_t)(m0 + r)*1024 + k0 + cc];
      const float4 bv = *(const float4*)&Wx[(size_t)(n0 + r)*1024 + k0 + cc];
      ushort4 ap, bp;
      ap.x = f2bf(av.x); ap.y = f2bf(av.y); ap.z = f2bf(av.z); ap.w = f2bf(av.w);
      bp.x = f2bf(bv.x); bp.y = f2bf(bv.y); bp.z = f2bf(bv.z); bp.w = f2bf(bv.w);
      *(ushort4*)&As[r*32 + cc] = ap;
      *(ushort4*)&Bs[r*32 + cc] = bp;
    }
    __syncthreads();
    short8 afr[4], bfr[4];
    #pragma unroll
    for (int mi = 0; mi < 4; ++mi)
      afr[mi] = *(const short8*)&As[(wm + mi*16 + fm)*32 + kq*8];
    #pragma unroll
    for (int ni = 0; ni < 4; ++ni)
      bfr[ni] = *(const short8*)&Bs[(wn + ni*16 + fm)*32 + kq*8];
    #pragma unroll
    for (int mi = 0; mi < 4; ++mi)
      #pragma unroll
      for (int ni = 0; ni < 4; ++ni)
        acc[mi][ni] = __builtin_amdgcn_mfma_f32_16x16x32_bf16(afr[mi], bfr[ni], acc[mi][ni], 0, 0, 0);
    __syncthreads();
  }
  const int cn = lane & 15, rb = (lane >> 4) << 2;
  #pragma unroll
  for (int mi = 0; mi < 4; ++mi) {
    #pragma unroll
    for (int ni = 0; ni < 4; ++ni) {
      const int n = n0 + wn + ni*16 + cn;
      const float bv = bias[n];
      #pragma unroll
      for (int r = 0; r < 4; ++r) {
        const int m = m0 + wm + mi*16 + rb + r;
        Apre[(size_t)m*1024 + n] = acc[mi][ni][r] + bv;
      }
    }
  }
}

// Persistent scan v8: v4's exact topology and detection (256 wgs = 16 batch x
// 16 slices, 1024 thr, 16-lane flag poll -- the only detection scheme that
// hasn't melted the fabric), with the producer's DOUBLE DRAIN merged into one:
//   v4 paid (a) barrier#3's implicit vmcnt(0) draining Phase-C epilogue stores,
//   THEN (b) wave-15 funnel: LDS read + 64 comm stores + s_waitcnt(0) (~900cy
//   at the measured HBM-latency comm path) + flag. (b) is redundant: producers
//   (kc==0 lanes, spread over all 16 waves) publish hall[t+1] DURING Phase C at
//   tanh-retire; barrier#3's compiler-guaranteed vmcnt(0)-before-s_barrier then
//   certifies ALL waves' publishes (HW-validated by v7 passing correctness with
//   flag-after-barrier), and tid0 stores the flag immediately. No funnel, no
//   second drain, no Phase D. Poll is sleep-free sticky per-lane (v7-style).
// Numerics: exact tanhf/expf (v4-identical; v7's fast-tanh doubled absmax).
__global__ __launch_bounds__(1024, 4) void scan_rnn(const float* __restrict__ Z,
                                                    const float* __restrict__ H0,
                                                    const u16* __restrict__ Weff,
                                                    float* __restrict__ outs,
                                                    float* __restrict__ hall,
                                                    u32* __restrict__ flg) {
  __shared__ __align__(16) float Hl[1024];   // h[t], float4 units XOR-swizzled
  __shared__ float hOwn[64];                 // own fresh slice (no self round trip)
  const int tid = threadIdx.x;
  const int b = blockIdx.x & 15;      // batch row (chain); all 16 slice-WGs of a
  const int s = blockIdx.x >> 4;      // chain land on one XCD under %8 round-robin
  const int d0 = s << 6;
  const int lane = tid & 63, wv = tid >> 6;
  const int kc = lane & 15;           // k-chunk of 64 floats
  const int kcl = kc & 7;
  const int dl = (wv << 2) + (lane >> 4);   // 0..63 dim within slice
  const int row = d0 + dl;

  // W row chunk in packed bf16 registers (32 VGPRs; proven resident in v4)
  uint4 w[8];
  {
    const uint4* Wg = (const uint4*)Weff;   // 128 uint4 per row
    #pragma unroll
    for (int j = 0; j < 8; ++j)
      w[j] = Wg[(size_t)row*128 + (kc << 3) + j];
  }

  // hall[0] slice (host output only)
  if (tid < 64)
    hall[(size_t)b*D_DIM + d0 + tid] = H0[b*D_DIM + d0 + tid];

  const float4* H4 = (const float4*)Hl;
  int pat = 1 << 21;                  // poll budget: deadlock -> clean finish, no hang

  for (int t = 0; t < T_STEPS; ++t) {
    const size_t base = (size_t)t*(BATCH*D_DIM) + (size_t)b*D_DIM + row;
    // Prefetch epilogue operands (addresses independent of h) -- overlap the poll
    float a_pre = 0.f, zv = 0.f;
    if (kc == 0) { a_pre = outs[base]; zv = Z[base]; }

    // Phase A: sticky per-lane flag poll, no sleep (wave 0, lanes 0..15).
    // Flag for h[t] (published end of step t-1) carries value t+1.
    if (t > 0 && wv == 0 && lane < 16 && lane != s) {
      const u32 tgt = (u32)(t + 1);
      u32 v;
      do {
        v = __hip_atomic_load(&flg[((b << 4) + lane) << 5],
                              __ATOMIC_RELAXED, __HIP_MEMORY_SCOPE_AGENT);
      } while (v < tgt && --pat > 0);
    }
    __syncthreads();

    // Phase B: stage h[t] into LDS. 256 threads x 16B; own chunk from hOwn.
    if (tid < 256) {
      const int unit = tid;           // float4 unit 0..255
      float4 hv;
      if (t == 0) {
        hv = ((const float4*)(H0 + (size_t)b*D_DIM))[unit];
      } else if ((unit >> 4) == s) {
        const float* ho = &hOwn[(unit & 15) << 2];
        hv.x = ho[0]; hv.y = ho[1]; hv.z = ho[2]; hv.w = ho[3];
      } else {
        const u64* h64 = (const u64*)(hall + (size_t)t*BATCH*D_DIM + (size_t)b*D_DIM);
        const u64 p0 = __hip_atomic_load(h64 + unit*2,     __ATOMIC_RELAXED, __HIP_MEMORY_SCOPE_AGENT);
        const u64 p1 = __hip_atomic_load(h64 + unit*2 + 1, __ATOMIC_RELAXED, __HIP_MEMORY_SCOPE_AGENT);
        hv.x = __uint_as_float((u32)p0); hv.y = __uint_as_float((u32)(p0 >> 32));
        hv.z = __uint_as_float((u32)p1); hv.w = __uint_as_float((u32)(p1 >> 32));
      }
      ((float4*)Hl)[unit ^ ((unit >> 4) & 7)] = hv;
    }
    __syncthreads();

    // Phase C: dot for dim row, k-chunk kc (64 elems), W from packed registers
    float acc = 0.f;
    #pragma unroll
    for (int j = 0; j < 8; ++j) {
      const uint4 w4 = w[j];
      const float4 ha = H4[(kc << 4) + (((j << 1)    ) ^ kcl)];
      const float4 hb = H4[(kc << 4) + (((j << 1) + 1) ^ kcl)];
      acc += bf_lo(w4.x)*ha.x + bf_hi(w4.x)*ha.y;
      acc += bf_lo(w4.y)*ha.z + bf_hi(w4.y)*ha.w;
      acc += bf_lo(w4.z)*hb.x + bf_hi(w4.z)*hb.y;
      acc += bf_lo(w4.w)*hb.z + bf_hi(w4.w)*hb.w;
    }
    // reduce across the 16 kc lanes (lane bits 0..3)
    acc += __shfl_xor(acc, 1, 64);
    acc += __shfl_xor(acc, 2, 64);
    acc += __shfl_xor(acc, 4, 64);
    acc += __shfl_xor(acc, 8, 64);

    if (kc == 0) {
      const float hn = tanhf(acc + a_pre);
      // Publish FIRST (critical path): direct agent store at tanh retire.
      __hip_atomic_store((u32*)&hall[base + BATCH*D_DIM], __float_as_uint(hn),
                         __ATOMIC_RELAXED, __HIP_MEMORY_SCOPE_AGENT);
      hOwn[dl] = hn;
      const float gate = zv / (1.f + expf(-zv));
      outs[base] = hn * gate;         // plain store (host-read only)
    }
    __syncthreads();   // implicit vmcnt(0) per wave: ALL publishes certified
    if (tid == 0)
      __hip_atomic_store(&flg[((b << 4) + s) << 5], (u32)(t + 2),
                         __ATOMIC_RELAXED, __HIP_MEMORY_SCOPE_AGENT);
  }
}

extern "C" void kernel_launch(void* const* d_in, const int* in_sizes, int n_in,
                              void* d_out, int out_size, void* d_ws, size_t ws_size,
                              hipStream_t stream) {
  const float* x  = (const float*)d_in[0];
  const float* z  = (const float*)d_in[1];
  const float* h0 = (const float*)d_in[2];
  const float* Wx = (const float*)d_in[3];
  const float* Wh = (const float*)d_in[4];
  const float* lr = (const float*)d_in[5];
  const float* bb = (const float*)d_in[6];
  const float* u0 = (const float*)d_in[7];

  float* outp = (float*)d_out;
  float* outs = outp;                                    // [1024][16][1024]
  float* hall = outp + (size_t)T_STEPS*BATCH*D_DIM;      // [1025][16][1024]

  char* ws = (char*)d_ws;
  u16* Weff = (u16*)ws;                         // 2 MiB bf16
  float* tA  = (float*)(ws + 2097152);
  float* tB  = (float*)(ws + 2101248);
  float* sg  = (float*)(ws + 2105344);
  u32* flg   = (u32*)(ws + 2105600);            // 256 flags, 128B apart = 32 KiB

  hipMemsetAsync(flg, 0, 256*128, stream);

  // 3-step power iteration (normalization folded into each matvec)
  mv_t<<<1024, 256, 0, stream>>>(Wh, u0, tA);   // v1_raw
  mv_n<<<1024, 256, 0, stream>>>(Wh, tA, tB);   // u1_raw
  mv_t<<<1024, 256, 0, stream>>>(Wh, tB, tA);   // v2_raw
  mv_n<<<1024, 256, 0, stream>>>(Wh, tA, tB);   // u2_raw
  mv_t<<<1024, 256, 0, stream>>>(Wh, tB, tA);   // v3_raw
  mv_n<<<1024, 256, 0, stream>>>(Wh, tA, tB);   // u3_raw = W v3
  sigma_k<<<1, 256, 0, stream>>>(tB, sg);
  make_weff<<<1024, 256, 0, stream>>>(Wh, lr, sg, Weff);

  // A_pre = x @ Wx^T + b, written into the outs region (overwritten in-place by scan)
  gemm_xwT<<<1024, 256, 0, stream>>>(x, Wx, bb, outs);

  // Persistent sequential scan: single-drain producer path, v4 detection
  scan_rnn<<<256, 1024, 0, stream>>>(z, h0, Weff, outs, hall, flg);
}